// Round 9
// baseline (187.940 us; speedup 1.0000x reference)
//
#include <hip/hip_runtime.h>

#define NB 16
#define NC 256
#define NH 56
#define NW 56
#define NHW (NH * NW)          // 3136
#define NK 256
#define TK_THREADS 1024
#define CAP 1024

// pass1 geometry: 4-row band x half the channels per block -> 448 blocks
#define BR 4                   // compute rows per band
#define RS 6                   // staged rows (4 compute + 2 halo)
#define CS 16                  // channels per staged chunk
#define CHALF 128              // channels per block
#define NCHUNK_H (CHALF / CS)  // 8 chunks per block
#define CHUNK16 (CS * RS * NW / 4)        // 1344 16B-chunks per stage
#define NBAND (NH / BR)                   // 14
#define P1_BLOCKS (NB * NBAND * 2)        // 448 (56 per XCD)
#define NQ (BR * (NW / 4))                // 56 quads per band
#define MAPS (NB * NHW)                   // elements per map

// ---- sortable-float helpers -------------------------------------------------
__device__ inline unsigned int flip_f32(float f) {
    unsigned int u = __float_as_uint(f);
    return (u & 0x80000000u) ? ~u : (u | 0x80000000u);
}
__device__ inline float unflip_f32(unsigned int u) {
    u = (u & 0x80000000u) ? (u ^ 0x80000000u) : ~u;
    return __uint_as_float(u);
}

// ---- kernel 1: partial norm2 / hprod / vprod maps ---------------------------
// Block = (batch, 4-row band, channel-half). 6 staged rows per 4 produced
// (1.5x amplification, 77 MB total vs R6's 103 MB) while KEEPING 448 blocks
// (R7's 224-block version starved 32 CUs and lost stage/compute overlap).
// Each block writes its channel-half partial maps; topk sums the two halves
// in fixed order (deterministic).
__global__ void __launch_bounds__(256)
pass1_kernel(const float* __restrict__ f, float* __restrict__ maps) {
    __shared__ __align__(16) float buf[2][CS * RS * NW];   // 2 x 21504 B
    __shared__ float redbuf[NQ][4][12];                    // 10752 B

    int bid = blockIdx.x;
    int sb = (bid & 7) * (P1_BLOCKS / 8) + (bid >> 3);   // XCD-chunked
    int b = sb / 28;
    int rem0 = sb - b * 28;
    int band = rem0 >> 1;
    int chh = rem0 & 1;            // channel half: both halves of a band on same XCD
    int y0 = band * BR;
    int tid = threadIdx.x;
    const float* fb = f + (size_t)b * NC * NHW + (size_t)chh * CHALF * NHW;

    auto stage = [&](int ci, float* dst) {
        int c0 = ci * CS;
#pragma unroll
        for (int i = 0; i < 6; ++i) {
            int k = tid + 256 * i;
            if (k < CHUNK16) {
                int ch = k / (RS * 14);            // 84 16B-chunks per channel
                int rem = k - ch * (RS * 14);
                int rl = rem / 14;                 // staged row 0..5
                int xk = rem - rl * 14;            // 16B chunk within row
                int rg = y0 - 1 + rl;
                rg = rg < 0 ? 0 : (rg > NH - 1 ? NH - 1 : rg);
                const float* src = fb + (size_t)(c0 + ch) * NHW + rg * NW + xk * 4;
                __builtin_amdgcn_global_load_lds(
                    (const __attribute__((address_space(1))) void*)src,
                    (__attribute__((address_space(3))) void*)(dst + k * 4),
                    16, 0, 0);
            }
        }
    };

    // compute geometry: tid<224 -> quad (4 rows x 14 quads) x chgroup(4)
    int chg = tid / NQ;                 // 0..3, each handles 4 ch per chunk
    int quad = tid - chg * NQ;          // 0..55
    int r = quad / 14, qx = quad - r * 14, x0 = qx * 4;
    int xl = x0 ? x0 - 1 : 0;
    int xr = (x0 + 4 < NW) ? x0 + 4 : NW - 1;

    float n0 = 0.f, n1 = 0.f, n2 = 0.f, n3 = 0.f;
    float h0 = 0.f, h1 = 0.f, h2 = 0.f, h3 = 0.f;
    float w0 = 0.f, w1 = 0.f, w2 = 0.f, w3 = 0.f;

    stage(0, buf[0]);
    __syncthreads();                            // drains staging
    for (int ci = 0; ci < NCHUNK_H; ++ci) {
        if (ci + 1 < NCHUNK_H) stage(ci + 1, buf[(ci + 1) & 1]);
        if (tid < 4 * NQ) {
            const float* sbf = buf[ci & 1];
#pragma unroll
            for (int c = 0; c < 4; ++c) {
                const float* Bm = sbf + (chg * 4 + c) * (RS * NW) + (r + 1) * NW;
                float4 v = *(const float4*)(Bm + x0);
                float  l = Bm[xl];
                float  rr = Bm[xr];
                float4 u = *(const float4*)(Bm + NW + x0);   // global y+1
                float4 d = *(const float4*)(Bm - NW + x0);   // global y-1
                n0 += v.x * v.x; n1 += v.y * v.y; n2 += v.z * v.z; n3 += v.w * v.w;
                h0 += l * v.y;   h1 += v.x * v.z; h2 += v.y * v.w; h3 += v.z * rr;
                w0 += u.x * d.x; w1 += u.y * d.y; w2 += u.z * d.z; w3 += u.w * d.w;
            }
        }
        __syncthreads();   // compute done + next stage landed
    }

    if (tid < 4 * NQ) {
        float* rb = redbuf[quad][chg];
        rb[0] = n0; rb[1] = n1; rb[2]  = n2; rb[3]  = n3;
        rb[4] = h0; rb[5] = h1; rb[6]  = h2; rb[7]  = h3;
        rb[8] = w0; rb[9] = w1; rb[10] = w2; rb[11] = w3;
    }
    __syncthreads();

    // maps layout: [chh][comp-class][B*HW]: n,h,v for half0 then half1
    float* mbase = maps + (size_t)chh * 3 * MAPS;
    for (int oi = tid; oi < NQ * 12; oi += 256) {
        int q = oi / 12, comp = oi - q * 12;
        float acc = 0.f;
#pragma unroll
        for (int g = 0; g < 4; ++g) acc += redbuf[q][g][comp];
        int r2 = q / 14, qx2 = q - r2 * 14;
        int j = comp & 3;
        float* m = mbase + (size_t)(comp >> 2) * MAPS;   // 0:n 1:h 2:v
        m[((size_t)b * NH + y0 + r2) * NW + qx2 * 4 + j] = acc;
    }
}

// ---- kernel 2: fused sim-finish + per-batch top-K ---------------------------
// Sums the two channel-half partial maps in fixed order (h0+h1 etc.), then
// radix-select + bitonic as before.
__global__ void __launch_bounds__(TK_THREADS)
topk_kernel(const float* __restrict__ maps, int* __restrict__ idx_out,
            float* __restrict__ vals_out, float* __restrict__ y_out,
            float* __restrict__ x_out) {
    __shared__ float nsh[NHW];
    __shared__ unsigned int svals[NHW];          // flipped sim values
    __shared__ unsigned int hist16[16][256];     // per-wave histograms
    __shared__ unsigned long long cand[CAP];
    __shared__ unsigned int sh_prefix, sh_mask;
    __shared__ int sh_cnt, sh_above, sh_setS, sh_done;

    const int b = blockIdx.x;
    const int tid = threadIdx.x;
    const int lane = tid & 63;
    const int wv = tid >> 6;
    const float* na = maps + (size_t)b * NHW;
    const float* ha = na + MAPS;
    const float* va = na + 2 * (size_t)MAPS;
    const float* nb2 = na + 3 * (size_t)MAPS;
    const float* hb2 = na + 4 * (size_t)MAPS;
    const float* vb2 = na + 5 * (size_t)MAPS;

    for (int i = tid; i < NHW; i += TK_THREADS) nsh[i] = na[i] + nb2[i];
    if (tid == 0) { sh_prefix = 0u; sh_mask = 0u; sh_above = 0; sh_done = 0; }
    __syncthreads();

    for (int i = tid; i < NHW; i += TK_THREADS) {
        int y = i / NW, x = i - y * NW;
        int xl = (x > 0) ? x - 1 : 0;
        int xr = (x < NW - 1) ? x + 1 : NW - 1;
        int yu = (y < NH - 1) ? y + 1 : NH - 1;
        int yd = (y > 0) ? y - 1 : 0;
        float h = ha[i] + hb2[i], v = va[i] + vb2[i];
        float s = 0.5f * (h / (sqrtf(nsh[y * NW + xl]) * sqrtf(nsh[y * NW + xr])) +
                          v / (sqrtf(nsh[yu * NW + x]) * sqrtf(nsh[yd * NW + x])));
        svals[i] = flip_f32(s);
    }

    // progressive 8-bit radix-select: exact threshold prefix T with
    // #{v >= T} in [NK, 512] (or full 32-bit refinement on heavy ties)
    int shift = 24;
    for (int stage = 0; stage < 4; ++stage) {
        __syncthreads();
        if (sh_done) break;
        for (int i = tid; i < 16 * 256; i += TK_THREADS) ((unsigned int*)hist16)[i] = 0u;
        __syncthreads();
        unsigned int pfx = sh_prefix, msk = sh_mask;
        for (int i = tid; i < NHW; i += TK_THREADS) {
            unsigned int v = svals[i];
            if ((v & msk) == pfx) atomicAdd(&hist16[wv][(v >> shift) & 255u], 1u);
        }
        __syncthreads();
        if (tid < 64) {                 // wave 0: parallel suffix-scan + pick
            int l = tid;
            unsigned int kneed = (unsigned int)(NK - sh_above);
            unsigned int h0 = 0, h1 = 0, h2 = 0, h3 = 0;
#pragma unroll
            for (int w = 0; w < 16; ++w) {
                h0 += hist16[w][4 * l + 0]; h1 += hist16[w][4 * l + 1];
                h2 += hist16[w][4 * l + 2]; h3 += hist16[w][4 * l + 3];
            }
            unsigned int lsum = h0 + h1 + h2 + h3;
            unsigned int s = lsum;
#pragma unroll
            for (int d = 1; d < 64; d <<= 1) {
                unsigned int t = __shfl_down(s, d);
                s += (l + d < 64) ? t : 0u;
            }
            unsigned int above_l = s - lsum;      // digits in lanes > l
            unsigned int suf3 = above_l + h3;
            unsigned int suf2 = suf3 + h2;
            unsigned int suf1 = suf2 + h1;
            unsigned int suf0 = suf1 + h0;
            bool has = (suf0 >= kneed);
            unsigned long long bal = __ballot(has);
            int hl = 63 - __clzll(bal);           // highest lane with a hit
            if (l == hl) {
                int c; unsigned int above, hc;
                if (suf3 >= kneed)      { c = 4 * l + 3; above = above_l; hc = h3; }
                else if (suf2 >= kneed) { c = 4 * l + 2; above = suf3;    hc = h2; }
                else if (suf1 >= kneed) { c = 4 * l + 1; above = suf2;    hc = h1; }
                else                    { c = 4 * l + 0; above = suf1;    hc = h0; }
                sh_above += (int)above;
                sh_setS = (int)hc;
                sh_prefix |= ((unsigned int)c) << shift;
                sh_mask   |= 255u << shift;
                if (sh_above + sh_setS <= 512 || shift == 0) sh_done = 1;
            }
        }
        shift -= 8;
    }
    __syncthreads();

    // ballot-aggregated compaction of candidates v >= T
    if (tid == 0) sh_cnt = 0;
    __syncthreads();
    unsigned int T = sh_prefix;
    for (int i = tid; i < NHW; i += TK_THREADS) {
        unsigned int v = svals[i];
        bool keep = (v >= T);
        unsigned long long m = __ballot(keep);
        int basep = 0;
        if (lane == 0) basep = atomicAdd(&sh_cnt, __popcll(m));
        basep = __shfl(basep, 0);
        if (keep) {
            int pos = basep + __popcll(m & ((1ull << lane) - 1ull));
            if (pos < CAP)
                cand[pos] = ((unsigned long long)v << 32) |
                            (unsigned long long)(0xFFFFFFFFu - (unsigned int)i);
        }
    }
    __syncthreads();
    int nc = sh_cnt; if (nc > CAP) nc = CAP;
    const int NS = (nc <= 512) ? 512 : CAP;
    for (int i = tid; i < NS; i += TK_THREADS) if (i >= nc) cand[i] = 0ull;
    __syncthreads();

    // bitonic sort NS keys descending
    for (int k = 2; k <= NS; k <<= 1) {
        for (int j = k >> 1; j > 0; j >>= 1) {
            for (int i = tid; i < NS; i += TK_THREADS) {
                int ixj = i ^ j;
                if (ixj > i) {
                    unsigned long long a = cand[i], c2 = cand[ixj];
                    bool sw = ((i & k) == 0) ? (a < c2) : (a > c2);
                    if (sw) { cand[i] = c2; cand[ixj] = a; }
                }
            }
            __syncthreads();
        }
    }

    if (tid < NK) {
        unsigned long long kk = cand[tid];
        unsigned int lo = (unsigned int)(kk & 0xFFFFFFFFull);
        int idx = (int)(0xFFFFFFFFu - lo);
        float val = unflip_f32((unsigned int)(kk >> 32));
        int o = b * NK + tid;
        idx_out[o] = idx;
        vals_out[o] = val;
        y_out[o] = (float)(idx / NW);
        x_out[o] = (float)(idx % NW);
    }
}

// ---- kernel 3: gather point features [B,K,C] --------------------------------
// MEASUREMENT ROUND: launched 9x (idempotent) -> dur = base + 8*gather.
__global__ void gather_kernel(const float* __restrict__ f, const int* __restrict__ idx,
                              float* __restrict__ out) {
    int blk = blockIdx.x;          // b*NK + k
    int b = blk >> 8;              // NK == 256
    int p = idx[blk];
    out[(size_t)blk * NC + threadIdx.x] =
        f[(size_t)b * NC * NHW + (size_t)threadIdx.x * NHW + (size_t)p];
}

extern "C" void kernel_launch(void* const* d_in, const int* in_sizes, int n_in,
                              void* d_out, int out_size, void* d_ws, size_t ws_size,
                              hipStream_t stream) {
    const float* f = (const float*)d_in[0];

    // output layout: point_feat [B,K,C] | vals [B,K] | ycoord [B,K] | xcoord [B,K]
    float* out_feat = (float*)d_out;
    float* out_vals = out_feat + (size_t)NB * NK * NC;
    float* out_y    = out_vals + (size_t)NB * NK;
    float* out_x    = out_y    + (size_t)NB * NK;

    // workspace: 6 partial maps (n,h,v for each channel-half) | idx
    float* maps = (float*)d_ws;
    int*   idx  = (int*)(maps + 6 * (size_t)MAPS);

    pass1_kernel<<<P1_BLOCKS, 256, 0, stream>>>(f, maps);
    topk_kernel<<<NB, TK_THREADS, 0, stream>>>(maps, idx, out_vals, out_y, out_x);
    // MEASUREMENT: 9 idempotent gather launches
    for (int rep = 0; rep < 9; ++rep)
        gather_kernel<<<NB * NK, NC, 0, stream>>>(f, idx, out_feat);
}

// Round 10
// 43.138 us; speedup vs baseline: 4.3567x; 4.3567x over previous
//
#include <hip/hip_runtime.h>

#define NB 16
#define NC 256
#define NH 56
#define NW 56
#define NHW (NH * NW)          // 3136
#define NK 256
#define TK_THREADS 1024
#define CAP 1024

// pass1 geometry: 4-row band x half the channels per block -> 448 blocks
#define BR 4                   // compute rows per band
#define RS 6                   // staged rows (4 compute + 2 halo)
#define CS 16                  // channels per staged chunk
#define CHALF 128              // channels per block
#define NCHUNK_H (CHALF / CS)  // 8 chunks per block
#define CHUNK16 (CS * RS * NW / 4)        // 1344 16B-chunks per stage
#define NBAND (NH / BR)                   // 14
#define P1_BLOCKS (NB * NBAND * 2)        // 448 (56 per XCD)
#define NQ (BR * (NW / 4))                // 56 quads per band
#define MAPS (NB * NHW)                   // elements per map

// ---- sortable-float helpers -------------------------------------------------
__device__ inline unsigned int flip_f32(float f) {
    unsigned int u = __float_as_uint(f);
    return (u & 0x80000000u) ? ~u : (u | 0x80000000u);
}
__device__ inline float unflip_f32(unsigned int u) {
    u = (u & 0x80000000u) ? (u ^ 0x80000000u) : ~u;
    return __uint_as_float(u);
}

// ---- kernel 1: partial norm2 / hprod / vprod maps (R9-exact) ----------------
__global__ void __launch_bounds__(256)
pass1_kernel(const float* __restrict__ f, float* __restrict__ maps) {
    __shared__ __align__(16) float buf[2][CS * RS * NW];   // 2 x 21504 B
    __shared__ float redbuf[NQ][4][12];                    // 10752 B

    int bid = blockIdx.x;
    int sb = (bid & 7) * (P1_BLOCKS / 8) + (bid >> 3);   // XCD-chunked
    int b = sb / 28;
    int rem0 = sb - b * 28;
    int band = rem0 >> 1;
    int chh = rem0 & 1;            // channel half
    int y0 = band * BR;
    int tid = threadIdx.x;
    const float* fb = f + (size_t)b * NC * NHW + (size_t)chh * CHALF * NHW;

    auto stage = [&](int ci, float* dst) {
        int c0 = ci * CS;
#pragma unroll
        for (int i = 0; i < 6; ++i) {
            int k = tid + 256 * i;
            if (k < CHUNK16) {
                int ch = k / (RS * 14);            // 84 16B-chunks per channel
                int rem = k - ch * (RS * 14);
                int rl = rem / 14;                 // staged row 0..5
                int xk = rem - rl * 14;            // 16B chunk within row
                int rg = y0 - 1 + rl;
                rg = rg < 0 ? 0 : (rg > NH - 1 ? NH - 1 : rg);
                const float* src = fb + (size_t)(c0 + ch) * NHW + rg * NW + xk * 4;
                __builtin_amdgcn_global_load_lds(
                    (const __attribute__((address_space(1))) void*)src,
                    (__attribute__((address_space(3))) void*)(dst + k * 4),
                    16, 0, 0);
            }
        }
    };

    // compute geometry: tid<224 -> quad (4 rows x 14 quads) x chgroup(4)
    int chg = tid / NQ;                 // 0..3, each handles 4 ch per chunk
    int quad = tid - chg * NQ;          // 0..55
    int r = quad / 14, qx = quad - r * 14, x0 = qx * 4;
    int xl = x0 ? x0 - 1 : 0;
    int xr = (x0 + 4 < NW) ? x0 + 4 : NW - 1;

    float n0 = 0.f, n1 = 0.f, n2 = 0.f, n3 = 0.f;
    float h0 = 0.f, h1 = 0.f, h2 = 0.f, h3 = 0.f;
    float w0 = 0.f, w1 = 0.f, w2 = 0.f, w3 = 0.f;

    stage(0, buf[0]);
    __syncthreads();                            // drains staging
    for (int ci = 0; ci < NCHUNK_H; ++ci) {
        if (ci + 1 < NCHUNK_H) stage(ci + 1, buf[(ci + 1) & 1]);
        if (tid < 4 * NQ) {
            const float* sbf = buf[ci & 1];
#pragma unroll
            for (int c = 0; c < 4; ++c) {
                const float* Bm = sbf + (chg * 4 + c) * (RS * NW) + (r + 1) * NW;
                float4 v = *(const float4*)(Bm + x0);
                float  l = Bm[xl];
                float  rr = Bm[xr];
                float4 u = *(const float4*)(Bm + NW + x0);   // global y+1
                float4 d = *(const float4*)(Bm - NW + x0);   // global y-1
                n0 += v.x * v.x; n1 += v.y * v.y; n2 += v.z * v.z; n3 += v.w * v.w;
                h0 += l * v.y;   h1 += v.x * v.z; h2 += v.y * v.w; h3 += v.z * rr;
                w0 += u.x * d.x; w1 += u.y * d.y; w2 += u.z * d.z; w3 += u.w * d.w;
            }
        }
        __syncthreads();   // compute done + next stage landed
    }

    if (tid < 4 * NQ) {
        float* rb = redbuf[quad][chg];
        rb[0] = n0; rb[1] = n1; rb[2]  = n2; rb[3]  = n3;
        rb[4] = h0; rb[5] = h1; rb[6]  = h2; rb[7]  = h3;
        rb[8] = w0; rb[9] = w1; rb[10] = w2; rb[11] = w3;
    }
    __syncthreads();

    // maps layout: [chh][comp-class][B*HW]: n,h,v for half0 then half1
    float* mbase = maps + (size_t)chh * 3 * MAPS;
    for (int oi = tid; oi < NQ * 12; oi += 256) {
        int q = oi / 12, comp = oi - q * 12;
        float acc = 0.f;
#pragma unroll
        for (int g = 0; g < 4; ++g) acc += redbuf[q][g][comp];
        int r2 = q / 14, qx2 = q - r2 * 14;
        int j = comp & 3;
        float* m = mbase + (size_t)(comp >> 2) * MAPS;   // 0:n 1:h 2:v
        m[((size_t)b * NH + y0 + r2) * NW + qx2 * 4 + j] = acc;
    }
}

// ---- kernel 2: sim-finish (parallel, 196 blocks) ----------------------------
// Sums the two channel-half partials and computes flipped-sim u32 per pixel.
// FP expression order identical to R9's in-topk version.
__global__ void __launch_bounds__(256)
sim_kernel(const float* __restrict__ maps, unsigned int* __restrict__ sv) {
    int pix = blockIdx.x * 256 + threadIdx.x;
    if (pix >= NB * NHW) return;
    int b = pix / NHW, i = pix - b * NHW;
    const float* na  = maps + (size_t)b * NHW;
    const float* ha  = na + MAPS;
    const float* va  = na + 2 * (size_t)MAPS;
    const float* nb2 = na + 3 * (size_t)MAPS;
    const float* hb2 = na + 4 * (size_t)MAPS;
    const float* vb2 = na + 5 * (size_t)MAPS;

    int y = i / NW, x = i - y * NW;
    int xl = (x > 0) ? x - 1 : 0;
    int xr = (x < NW - 1) ? x + 1 : NW - 1;
    int yu = (y < NH - 1) ? y + 1 : NH - 1;
    int yd = (y > 0) ? y - 1 : 0;
    int il = y * NW + xl, ir = y * NW + xr;
    int iu = yu * NW + x, id = yd * NW + x;

    float nl = na[il] + nb2[il];
    float nr = na[ir] + nb2[ir];
    float nu = na[iu] + nb2[iu];
    float nd = na[id] + nb2[id];
    float h = ha[i] + hb2[i], v = va[i] + vb2[i];
    float s = 0.5f * (h / (sqrtf(nl) * sqrtf(nr)) + v / (sqrtf(nu) * sqrtf(nd)));
    sv[pix] = flip_f32(s);
}

// ---- kernel 3: per-batch top-K from precomputed svals -----------------------
// radix-select (exact threshold) + bitonic sort of <=CAP candidates.
// key = flip(val)<<32 | (0xFFFFFFFF - idx): descending sort == descending
// value, ties -> lower idx first (matches jax.lax.top_k).
__global__ void __launch_bounds__(TK_THREADS)
topk_kernel(const unsigned int* __restrict__ sv, int* __restrict__ idx_out,
            float* __restrict__ vals_out, float* __restrict__ y_out,
            float* __restrict__ x_out) {
    __shared__ unsigned int svals[NHW];          // flipped sim values
    __shared__ unsigned int hist16[16][256];     // per-wave histograms
    __shared__ unsigned long long cand[CAP];
    __shared__ unsigned int sh_prefix, sh_mask;
    __shared__ int sh_cnt, sh_above, sh_setS, sh_done;

    const int b = blockIdx.x;
    const int tid = threadIdx.x;
    const int lane = tid & 63;
    const int wv = tid >> 6;
    const unsigned int* svb = sv + (size_t)b * NHW;

    for (int i = tid; i < NHW; i += TK_THREADS) svals[i] = svb[i];
    if (tid == 0) { sh_prefix = 0u; sh_mask = 0u; sh_above = 0; sh_done = 0; }

    // progressive 8-bit radix-select: exact threshold prefix T with
    // #{v >= T} in [NK, 512] (or full 32-bit refinement on heavy ties)
    int shift = 24;
    for (int stage = 0; stage < 4; ++stage) {
        __syncthreads();
        if (sh_done) break;
        for (int i = tid; i < 16 * 256; i += TK_THREADS) ((unsigned int*)hist16)[i] = 0u;
        __syncthreads();
        unsigned int pfx = sh_prefix, msk = sh_mask;
        for (int i = tid; i < NHW; i += TK_THREADS) {
            unsigned int v = svals[i];
            if ((v & msk) == pfx) atomicAdd(&hist16[wv][(v >> shift) & 255u], 1u);
        }
        __syncthreads();
        if (tid < 64) {                 // wave 0: parallel suffix-scan + pick
            int l = tid;
            unsigned int kneed = (unsigned int)(NK - sh_above);
            unsigned int h0 = 0, h1 = 0, h2 = 0, h3 = 0;
#pragma unroll
            for (int w = 0; w < 16; ++w) {
                h0 += hist16[w][4 * l + 0]; h1 += hist16[w][4 * l + 1];
                h2 += hist16[w][4 * l + 2]; h3 += hist16[w][4 * l + 3];
            }
            unsigned int lsum = h0 + h1 + h2 + h3;
            unsigned int s = lsum;
#pragma unroll
            for (int d = 1; d < 64; d <<= 1) {
                unsigned int t = __shfl_down(s, d);
                s += (l + d < 64) ? t : 0u;
            }
            unsigned int above_l = s - lsum;      // digits in lanes > l
            unsigned int suf3 = above_l + h3;
            unsigned int suf2 = suf3 + h2;
            unsigned int suf1 = suf2 + h1;
            unsigned int suf0 = suf1 + h0;
            bool has = (suf0 >= kneed);
            unsigned long long bal = __ballot(has);
            int hl = 63 - __clzll(bal);           // highest lane with a hit
            if (l == hl) {
                int c; unsigned int above, hc;
                if (suf3 >= kneed)      { c = 4 * l + 3; above = above_l; hc = h3; }
                else if (suf2 >= kneed) { c = 4 * l + 2; above = suf3;    hc = h2; }
                else if (suf1 >= kneed) { c = 4 * l + 1; above = suf2;    hc = h1; }
                else                    { c = 4 * l + 0; above = suf1;    hc = h0; }
                sh_above += (int)above;
                sh_setS = (int)hc;
                sh_prefix |= ((unsigned int)c) << shift;
                sh_mask   |= 255u << shift;
                if (sh_above + sh_setS <= 512 || shift == 0) sh_done = 1;
            }
        }
        shift -= 8;
    }
    __syncthreads();

    // ballot-aggregated compaction of candidates v >= T
    if (tid == 0) sh_cnt = 0;
    __syncthreads();
    unsigned int T = sh_prefix;
    for (int i = tid; i < NHW; i += TK_THREADS) {
        unsigned int v = svals[i];
        bool keep = (v >= T);
        unsigned long long m = __ballot(keep);
        int basep = 0;
        if (lane == 0) basep = atomicAdd(&sh_cnt, __popcll(m));
        basep = __shfl(basep, 0);
        if (keep) {
            int pos = basep + __popcll(m & ((1ull << lane) - 1ull));
            if (pos < CAP)
                cand[pos] = ((unsigned long long)v << 32) |
                            (unsigned long long)(0xFFFFFFFFu - (unsigned int)i);
        }
    }
    __syncthreads();
    int nc = sh_cnt; if (nc > CAP) nc = CAP;
    const int NS = (nc <= 512) ? 512 : CAP;
    for (int i = tid; i < NS; i += TK_THREADS) if (i >= nc) cand[i] = 0ull;
    __syncthreads();

    // bitonic sort NS keys descending
    for (int k = 2; k <= NS; k <<= 1) {
        for (int j = k >> 1; j > 0; j >>= 1) {
            for (int i = tid; i < NS; i += TK_THREADS) {
                int ixj = i ^ j;
                if (ixj > i) {
                    unsigned long long a = cand[i], c2 = cand[ixj];
                    bool sw = ((i & k) == 0) ? (a < c2) : (a > c2);
                    if (sw) { cand[i] = c2; cand[ixj] = a; }
                }
            }
            __syncthreads();
        }
    }

    if (tid < NK) {
        unsigned long long kk = cand[tid];
        unsigned int lo = (unsigned int)(kk & 0xFFFFFFFFull);
        int idx = (int)(0xFFFFFFFFu - lo);
        float val = unflip_f32((unsigned int)(kk >> 32));
        int o = b * NK + tid;
        idx_out[o] = idx;
        vals_out[o] = val;
        y_out[o] = (float)(idx / NW);
        x_out[o] = (float)(idx % NW);
    }
}

// ---- kernel 4: gather point features [B,K,C] --------------------------------
// XCD-grouped: all blocks of batch b land on XCD (b&7) assuming round-robin
// dispatch (perf heuristic only) -> each batch's scattered lines are fetched
// into ONE XCD's L2 instead of all eight. 4 points per block -> 4 independent
// loads per thread (MLP), writes stay row-coalesced.
__global__ void __launch_bounds__(256)
gather_kernel(const float* __restrict__ f, const int* __restrict__ idx,
              float* __restrict__ out) {
    int bid = blockIdx.x;              // 1024
    int xcd = bid & 7, i = bid >> 3;   // i 0..127
    int b = xcd + 8 * (i & 1);
    int kg = i >> 1;                   // 0..63
    int c = threadIdx.x;
    const float* fb = f + (size_t)b * NC * NHW + (size_t)c * NHW;
#pragma unroll
    for (int j = 0; j < 4; ++j) {
        int k = kg * 4 + j;
        int p = idx[b * NK + k];       // uniform -> scalar load
        out[((size_t)b * NK + k) * NC + c] = fb[p];
    }
}

extern "C" void kernel_launch(void* const* d_in, const int* in_sizes, int n_in,
                              void* d_out, int out_size, void* d_ws, size_t ws_size,
                              hipStream_t stream) {
    const float* f = (const float*)d_in[0];

    // output layout: point_feat [B,K,C] | vals [B,K] | ycoord [B,K] | xcoord [B,K]
    float* out_feat = (float*)d_out;
    float* out_vals = out_feat + (size_t)NB * NK * NC;
    float* out_y    = out_vals + (size_t)NB * NK;
    float* out_x    = out_y    + (size_t)NB * NK;

    // workspace: 6 partial maps | svals map | idx
    float* maps = (float*)d_ws;
    unsigned int* sv = (unsigned int*)(maps + 6 * (size_t)MAPS);
    int* idx = (int*)(sv + MAPS);

    pass1_kernel<<<P1_BLOCKS, 256, 0, stream>>>(f, maps);
    sim_kernel<<<(NB * NHW + 255) / 256, 256, 0, stream>>>(maps, sv);
    topk_kernel<<<NB, TK_THREADS, 0, stream>>>(sv, idx, out_vals, out_y, out_x);
    gather_kernel<<<NB * NK / 4, 256, 0, stream>>>(f, idx, out_feat);
}